// Round 1
// baseline (286.972 us; speedup 1.0000x reference)
//
#include <hip/hip_runtime.h>

#define PH 7
#define PW 7
#define SP 4
#define C 10
#define CP 12              // channels padded to 12 -> 48B rows, 16B-aligned
#define FH 34
#define FW 34
#define NBIN (PH*PW)       // 49
#define PLANE (FH*FW)      // 1156

// ---- transpose (C,49,34,34) -> (49,34,34,CP) with zero padding ----
__global__ __launch_bounds__(256) void transpose_kernel(const float* __restrict__ src,
                                                        float* __restrict__ dst, int total) {
    int tid = blockIdx.x * blockDim.x + threadIdx.x;
    if (tid >= total) return;
    int c   = tid % CP;
    int t   = tid / CP;
    int yx  = t % PLANE;
    int bin = t / PLANE;
    float v = 0.0f;
    if (c < C) v = src[(c * NBIN + bin) * PLANE + yx];
    dst[tid] = v;
}

__device__ __forceinline__ void fma4(float4& a, float w, const float4 v) {
    a.x += w * v.x; a.y += w * v.y; a.z += w * v.z; a.w += w * v.w;
}

// ---- main kernel: one thread per (roi, bin), channels vectorized ----
__global__ __launch_bounds__(256) void roi_kernel(const float* __restrict__ featT,
                                                  const float* __restrict__ rois,
                                                  float* __restrict__ out, int N) {
#pragma clang fp contract(off)
    int tid = blockIdx.x * blockDim.x + threadIdx.x;
    if (tid >= N * NBIN) return;
    int bin = tid % NBIN;
    int n   = tid / NBIN;
    int ph  = bin / PW;
    int pw  = bin % PW;

    const float* r = rois + n * 5;
    float rsw = r[1] * 0.125f;
    float rsh = r[2] * 0.125f;
    float rew = r[3] * 0.125f;
    float reh = r[4] * 0.125f;

    float dh = reh - rsh; float roi_h = (dh > 0.1f) ? dh : 0.1f;
    float dw = rew - rsw; float roi_w = (dw > 0.1f) ? dw : 0.1f;
    float bin_h = roi_h / 7.0f;
    float bin_w = roi_w / 7.0f;
    float sub_h = bin_h / 4.0f;
    float sub_w = bin_w / 4.0f;
    float hstart = floorf(rsh + (float)ph * bin_h);
    float wstart = floorf(rsw + (float)pw * bin_w);

    float4 acc0 = make_float4(0.f,0.f,0.f,0.f);
    float4 acc1 = make_float4(0.f,0.f,0.f,0.f);
    float4 acc2 = make_float4(0.f,0.f,0.f,0.f);
    int count = 0;

    const float4* fp = (const float4*)featT + (size_t)bin * PLANE * 3;

    for (int sy = 0; sy < SP; ++sy) {
        float hh = hstart + ((float)sy + 0.5f) * sub_h;
        if (!(hh > -1.0f && hh < (float)FH)) continue;
        float y1f = floorf(hh);
        float y2f = ceilf(hh);
        float dy  = hh - y1f;
        int y1 = (int)y1f, y2 = (int)y2f;
        float y1ok = (y1 >= 0 && y1 < FH) ? 1.0f : 0.0f;
        float y2ok = (y2 >= 0 && y2 < FH) ? 1.0f : 0.0f;
        int y1c = min(max(y1, 0), FH - 1);
        int y2c = min(max(y2, 0), FH - 1);

        for (int sx = 0; sx < SP; ++sx) {
            float ww = wstart + ((float)sx + 0.5f) * sub_w;
            if (!(ww > -1.0f && ww < (float)FW)) continue;
            ++count;
            float x1f = floorf(ww);
            float x2f = ceilf(ww);
            float dx  = ww - x1f;
            int x1 = (int)x1f, x2 = (int)x2f;
            float x1ok = (x1 >= 0 && x1 < FW) ? 1.0f : 0.0f;
            float x2ok = (x2 >= 0 && x2 < FW) ? 1.0f : 0.0f;
            int x1c = min(max(x1, 0), FW - 1);
            int x2c = min(max(x2, 0), FW - 1);

            float w11 = (1.0f - dx) * (1.0f - dy) * x1ok * y1ok;
            float w12 = (1.0f - dx) * dy          * x1ok * y2ok;
            float w21 = dx * (1.0f - dy)          * x2ok * y1ok;
            float w22 = dx * dy                   * x2ok * y2ok;

            const float4* p11 = fp + (y1c * FW + x1c) * 3;
            const float4* p12 = fp + (y2c * FW + x1c) * 3;
            const float4* p21 = fp + (y1c * FW + x2c) * 3;
            const float4* p22 = fp + (y2c * FW + x2c) * 3;

            fma4(acc0, w11, p11[0]); fma4(acc1, w11, p11[1]); fma4(acc2, w11, p11[2]);
            fma4(acc0, w12, p12[0]); fma4(acc1, w12, p12[1]); fma4(acc2, w12, p12[2]);
            fma4(acc0, w21, p21[0]); fma4(acc1, w21, p21[1]); fma4(acc2, w21, p21[2]);
            fma4(acc0, w22, p22[0]); fma4(acc1, w22, p22[1]); fma4(acc2, w22, p22[2]);
        }
    }

    float* o = out + (size_t)n * (C * NBIN) + bin;
    if (count > 0) {
        float inv = 1.0f / (float)count;
        o[0 * NBIN] = acc0.x * inv;
        o[1 * NBIN] = acc0.y * inv;
        o[2 * NBIN] = acc0.z * inv;
        o[3 * NBIN] = acc0.w * inv;
        o[4 * NBIN] = acc1.x * inv;
        o[5 * NBIN] = acc1.y * inv;
        o[6 * NBIN] = acc1.z * inv;
        o[7 * NBIN] = acc1.w * inv;
        o[8 * NBIN] = acc2.x * inv;
        o[9 * NBIN] = acc2.y * inv;
    } else {
        for (int c = 0; c < C; ++c) o[c * NBIN] = 0.0f;
    }
}

// ---- fallback: read original layout directly (if ws too small) ----
__global__ __launch_bounds__(256) void roi_kernel_raw(const float* __restrict__ ft,
                                                      const float* __restrict__ rois,
                                                      float* __restrict__ out, int N) {
#pragma clang fp contract(off)
    int tid = blockIdx.x * blockDim.x + threadIdx.x;
    if (tid >= N * NBIN) return;
    int bin = tid % NBIN;
    int n   = tid / NBIN;
    int ph  = bin / PW;
    int pw  = bin % PW;

    const float* r = rois + n * 5;
    float rsw = r[1] * 0.125f;
    float rsh = r[2] * 0.125f;
    float rew = r[3] * 0.125f;
    float reh = r[4] * 0.125f;

    float dh = reh - rsh; float roi_h = (dh > 0.1f) ? dh : 0.1f;
    float dw = rew - rsw; float roi_w = (dw > 0.1f) ? dw : 0.1f;
    float bin_h = roi_h / 7.0f;
    float bin_w = roi_w / 7.0f;
    float sub_h = bin_h / 4.0f;
    float sub_w = bin_w / 4.0f;
    float hstart = floorf(rsh + (float)ph * bin_h);
    float wstart = floorf(rsw + (float)pw * bin_w);

    float acc[C];
    for (int c = 0; c < C; ++c) acc[c] = 0.0f;
    int count = 0;
    const float* base = ft + (size_t)bin * PLANE;

    for (int sy = 0; sy < SP; ++sy) {
        float hh = hstart + ((float)sy + 0.5f) * sub_h;
        if (!(hh > -1.0f && hh < (float)FH)) continue;
        float y1f = floorf(hh);
        float y2f = ceilf(hh);
        float dy  = hh - y1f;
        int y1 = (int)y1f, y2 = (int)y2f;
        float y1ok = (y1 >= 0 && y1 < FH) ? 1.0f : 0.0f;
        float y2ok = (y2 >= 0 && y2 < FH) ? 1.0f : 0.0f;
        int y1c = min(max(y1, 0), FH - 1);
        int y2c = min(max(y2, 0), FH - 1);

        for (int sx = 0; sx < SP; ++sx) {
            float ww = wstart + ((float)sx + 0.5f) * sub_w;
            if (!(ww > -1.0f && ww < (float)FW)) continue;
            ++count;
            float x1f = floorf(ww);
            float x2f = ceilf(ww);
            float dx  = ww - x1f;
            int x1 = (int)x1f, x2 = (int)x2f;
            float x1ok = (x1 >= 0 && x1 < FW) ? 1.0f : 0.0f;
            float x2ok = (x2 >= 0 && x2 < FW) ? 1.0f : 0.0f;
            int x1c = min(max(x1, 0), FW - 1);
            int x2c = min(max(x2, 0), FW - 1);

            float w11 = (1.0f - dx) * (1.0f - dy) * x1ok * y1ok;
            float w12 = (1.0f - dx) * dy          * x1ok * y2ok;
            float w21 = dx * (1.0f - dy)          * x2ok * y1ok;
            float w22 = dx * dy                   * x2ok * y2ok;

            int i11 = y1c * FW + x1c;
            int i12 = y2c * FW + x1c;
            int i21 = y1c * FW + x2c;
            int i22 = y2c * FW + x2c;

            for (int c = 0; c < C; ++c) {
                const float* pc = base + (size_t)c * NBIN * PLANE;
                acc[c] += w11 * pc[i11] + w12 * pc[i12] + w21 * pc[i21] + w22 * pc[i22];
            }
        }
    }

    float* o = out + (size_t)n * (C * NBIN) + bin;
    if (count > 0) {
        float inv = 1.0f / (float)count;
        for (int c = 0; c < C; ++c) o[c * NBIN] = acc[c] * inv;
    } else {
        for (int c = 0; c < C; ++c) o[c * NBIN] = 0.0f;
    }
}

extern "C" void kernel_launch(void* const* d_in, const int* in_sizes, int n_in,
                              void* d_out, int out_size, void* d_ws, size_t ws_size,
                              hipStream_t stream) {
    const float* ft   = (const float*)d_in[0];
    const float* rois = (const float*)d_in[1];
    float* out = (float*)d_out;
    int N = in_sizes[1] / 5;

    size_t need = (size_t)NBIN * PLANE * CP * sizeof(float);  // ~2.7 MB
    int total_work = N * NBIN;
    int blocks = (total_work + 255) / 256;

    if (ws_size >= need) {
        float* featT = (float*)d_ws;
        int total_t = NBIN * PLANE * CP;
        transpose_kernel<<<(total_t + 255) / 256, 256, 0, stream>>>(ft, featT, total_t);
        roi_kernel<<<blocks, 256, 0, stream>>>(featT, rois, out, N);
    } else {
        roi_kernel_raw<<<blocks, 256, 0, stream>>>(ft, rois, out, N);
    }
}

// Round 2
// 135.318 us; speedup vs baseline: 2.1207x; 2.1207x over previous
//
#include <hip/hip_runtime.h>

#define PH 7
#define PW 7
#define SP 4
#define C 10
#define CP 12              // channel pad -> 48B rows, 16B aligned in LDS
#define FH 34
#define FW 34
#define NBIN (PH*PW)       // 49
#define PLANE (FH*FW)      // 1156
#define RPB 256            // rois per block

// One block = (bin, chunk of 256 rois). Stage the bin's (34,34,CP) slab in
// LDS (55.5 KB -> 2 blocks/CU), then each thread does one roi via the
// separable 3x3-window reduction: 9 LDS pixel reads instead of 64 corner
// gathers through L1.
__global__ __launch_bounds__(256) void roi_kernel(const float* __restrict__ ft,
                                                  const float* __restrict__ rois,
                                                  float* __restrict__ out,
                                                  int N, int blocksPerBin) {
#pragma clang fp contract(off)
    __shared__ float lds[PLANE * CP];

    const int bin   = blockIdx.x / blocksPerBin;
    const int chunk = blockIdx.x % blocksPerBin;
    const int tid   = threadIdx.x;
    const int ph    = bin / PW;
    const int pw    = bin % PW;

    // ---- stage slab: lds[(y*FW+x)*CP + c], coalesced global reads per plane
    for (int c = 0; c < C; ++c) {
        const float* src = ft + ((size_t)c * NBIN + bin) * PLANE;
        for (int yx = tid; yx < PLANE; yx += RPB)
            lds[yx * CP + c] = src[yx];
    }
    for (int yx = tid; yx < PLANE; yx += RPB) {
        lds[yx * CP + 10] = 0.0f;
        lds[yx * CP + 11] = 0.0f;
    }
    __syncthreads();

    const int n = chunk * RPB + tid;
    if (n >= N) return;

    const float* r = rois + n * 5;
    float rsw = r[1] * 0.125f;
    float rsh = r[2] * 0.125f;
    float rew = r[3] * 0.125f;
    float reh = r[4] * 0.125f;

    float dh = reh - rsh; float roi_h = (dh > 0.1f) ? dh : 0.1f;
    float dw = rew - rsw; float roi_w = (dw > 0.1f) ? dw : 0.1f;
    float bin_h = roi_h / 7.0f;
    float bin_w = roi_w / 7.0f;
    float sub_h = bin_h / 4.0f;
    float sub_w = bin_w / 4.0f;
    float hstart = floorf(rsh + (float)ph * bin_h);
    float wstart = floorf(rsw + (float)pw * bin_w);
    const int X0 = (int)hstart == (int)hstart ? (int)wstart : (int)wstart; // (int)wstart
    const int Y0 = (int)hstart;

    // ---- separable per-axis accumulated weights over the 3-wide window
    float cw0 = 0.f, cw1 = 0.f, cw2 = 0.f; int cntx = 0;
#pragma unroll
    for (int s = 0; s < SP; ++s) {
        float ww = wstart + ((float)s + 0.5f) * sub_w;
        if (ww > -1.0f && ww < (float)FW) {
            ++cntx;
            float x1f = floorf(ww);
            float dx  = ww - x1f;
            int   x1  = (int)x1f;
            int   x2  = (int)ceilf(ww);
            float w1  = (1.0f - dx) * ((x1 >= 0 && x1 < FW) ? 1.0f : 0.0f);
            float w2  = dx          * ((x2 >= 0 && x2 < FW) ? 1.0f : 0.0f);
            int o1 = x1 - X0;       // in {0,1}
            int o2 = x2 - X0;       // in {0,1,2}; when o2==o1 (integer ww), w2==0
            cw0 += (o1 == 0) ? w1 : 0.0f;
            cw1 += (o1 == 1) ? w1 : 0.0f;
            cw1 += (o2 == 1) ? w2 : 0.0f;
            cw2 += (o2 == 2) ? w2 : 0.0f;
        }
    }
    float rw0 = 0.f, rw1 = 0.f, rw2 = 0.f; int cnty = 0;
#pragma unroll
    for (int s = 0; s < SP; ++s) {
        float hh = hstart + ((float)s + 0.5f) * sub_h;
        if (hh > -1.0f && hh < (float)FH) {
            ++cnty;
            float y1f = floorf(hh);
            float dy  = hh - y1f;
            int   y1  = (int)y1f;
            int   y2  = (int)ceilf(hh);
            float w1  = (1.0f - dy) * ((y1 >= 0 && y1 < FH) ? 1.0f : 0.0f);
            float w2  = dy          * ((y2 >= 0 && y2 < FH) ? 1.0f : 0.0f);
            int o1 = y1 - Y0;
            int o2 = y2 - Y0;
            rw0 += (o1 == 0) ? w1 : 0.0f;
            rw1 += (o1 == 1) ? w1 : 0.0f;
            rw1 += (o2 == 1) ? w2 : 0.0f;
            rw2 += (o2 == 2) ? w2 : 0.0f;
        }
    }

    // ---- 3x3 window accumulate: 9 LDS pixel reads x 10 channels
    float4 a0 = make_float4(0.f,0.f,0.f,0.f);
    float4 a1 = make_float4(0.f,0.f,0.f,0.f);
    float  a8 = 0.f, a9 = 0.f;
    float rw[3] = {rw0, rw1, rw2};
    float cw[3] = {cw0, cw1, cw2};
#pragma unroll
    for (int j = 0; j < 3; ++j) {
        int y = min(max(Y0 + j, 0), FH - 1);
        float wy = rw[j];
#pragma unroll
        for (int i = 0; i < 3; ++i) {
            int x = min(max(X0 + i, 0), FW - 1);
            float w = wy * cw[i];
            const float4* lp = (const float4*)(lds + (y * FW + x) * CP);
            float4 f0 = lp[0];
            float4 f1 = lp[1];
            float4 f2 = lp[2];
            a0.x += w * f0.x; a0.y += w * f0.y; a0.z += w * f0.z; a0.w += w * f0.w;
            a1.x += w * f1.x; a1.y += w * f1.y; a1.z += w * f1.z; a1.w += w * f1.w;
            a8   += w * f2.x; a9   += w * f2.y;
        }
    }

    int cnt = cntx * cnty;
    float* o = out + (size_t)n * (C * NBIN) + bin;
    if (cnt > 0) {
        float inv = 1.0f / (float)cnt;
        o[0 * NBIN] = a0.x * inv;
        o[1 * NBIN] = a0.y * inv;
        o[2 * NBIN] = a0.z * inv;
        o[3 * NBIN] = a0.w * inv;
        o[4 * NBIN] = a1.x * inv;
        o[5 * NBIN] = a1.y * inv;
        o[6 * NBIN] = a1.z * inv;
        o[7 * NBIN] = a1.w * inv;
        o[8 * NBIN] = a8   * inv;
        o[9 * NBIN] = a9   * inv;
    } else {
#pragma unroll
        for (int c = 0; c < C; ++c) o[c * NBIN] = 0.0f;
    }
}

extern "C" void kernel_launch(void* const* d_in, const int* in_sizes, int n_in,
                              void* d_out, int out_size, void* d_ws, size_t ws_size,
                              hipStream_t stream) {
    const float* ft   = (const float*)d_in[0];
    const float* rois = (const float*)d_in[1];
    float* out = (float*)d_out;
    int N = in_sizes[1] / 5;

    int blocksPerBin = (N + RPB - 1) / RPB;
    int nblocks = NBIN * blocksPerBin;
    roi_kernel<<<nblocks, RPB, 0, stream>>>(ft, rois, out, N, blocksPerBin);
}

// Round 3
// 116.424 us; speedup vs baseline: 2.4649x; 1.1623x over previous
//
#include <hip/hip_runtime.h>

#define PH 7
#define PW 7
#define SP 4
#define C 10
#define CP 12              // channel pad -> 48B rows, 16B aligned in LDS
#define FH 34
#define FW 34
#define NBIN (PH*PW)       // 49
#define PLANE (FH*FW)      // 1156
#define RPB 256            // rois per block
#define NOUTC (C*NBIN)     // 490

// One block = (bin, chunk of 256 rois). Stage the bin's (34,34,CP) slab in LDS
// via conflict-free ds_write_b128, then each thread does one roi via the
// separable 3x3-window reduction (9 LDS pixel reads).
// If transposed==1, store to ws[(bin*C+c)*N + n] (coalesced, fixed up by
// transpose_out); else store directly to out[n*490 + c*49 + bin] (slow path).
__global__ __launch_bounds__(256) void roi_kernel(const float* __restrict__ ft,
                                                  const float* __restrict__ rois,
                                                  float* __restrict__ dst,
                                                  int N, int blocksPerBin,
                                                  int transposed) {
#pragma clang fp contract(off)
    __shared__ float lds[PLANE * CP];

    const int bin   = blockIdx.x / blocksPerBin;
    const int chunk = blockIdx.x % blocksPerBin;
    const int tid   = threadIdx.x;
    const int ph    = bin / PW;
    const int pw    = bin % PW;

    // ---- stage slab as float4 quads: lds4[yx*3+q] = channels {4q..4q+3} of yx.
    // Linear float4 address per lane -> conflict-free b128 writes.
    {
        float4* lds4 = (float4*)lds;
        const float* base = ft + (size_t)bin * PLANE;
        for (int idx = tid; idx < PLANE * 3; idx += RPB) {
            int yx = idx / 3;
            int q  = idx - yx * 3;
            int c0 = q * 4;
            float4 v;
            v.x = base[(size_t)(c0 + 0) * NBIN * PLANE + yx];
            v.y = base[(size_t)(c0 + 1) * NBIN * PLANE + yx];
            v.z = (c0 + 2 < C) ? base[(size_t)(c0 + 2) * NBIN * PLANE + yx] : 0.0f;
            v.w = (c0 + 3 < C) ? base[(size_t)(c0 + 3) * NBIN * PLANE + yx] : 0.0f;
            lds4[idx] = v;
        }
    }
    __syncthreads();

    const int n = chunk * RPB + tid;
    if (n >= N) return;

    const float* r = rois + n * 5;
    float rsw = r[1] * 0.125f;
    float rsh = r[2] * 0.125f;
    float rew = r[3] * 0.125f;
    float reh = r[4] * 0.125f;

    float dh = reh - rsh; float roi_h = (dh > 0.1f) ? dh : 0.1f;
    float dw = rew - rsw; float roi_w = (dw > 0.1f) ? dw : 0.1f;
    float bin_h = roi_h / 7.0f;
    float bin_w = roi_w / 7.0f;
    float sub_h = bin_h / 4.0f;
    float sub_w = bin_w / 4.0f;
    float hstart = floorf(rsh + (float)ph * bin_h);
    float wstart = floorf(rsw + (float)pw * bin_w);
    const int X0 = (int)wstart;
    const int Y0 = (int)hstart;

    // ---- separable per-axis accumulated weights over the 3-wide window
    float cw0 = 0.f, cw1 = 0.f, cw2 = 0.f; int cntx = 0;
#pragma unroll
    for (int s = 0; s < SP; ++s) {
        float ww = wstart + ((float)s + 0.5f) * sub_w;
        if (ww > -1.0f && ww < (float)FW) {
            ++cntx;
            float x1f = floorf(ww);
            float dx  = ww - x1f;
            int   x1  = (int)x1f;
            int   x2  = (int)ceilf(ww);
            float w1  = (1.0f - dx) * ((x1 >= 0 && x1 < FW) ? 1.0f : 0.0f);
            float w2  = dx          * ((x2 >= 0 && x2 < FW) ? 1.0f : 0.0f);
            int o1 = x1 - X0;       // in {0,1}
            int o2 = x2 - X0;       // in {0,1,2}; when o2==o1 (integer ww), w2==0
            cw0 += (o1 == 0) ? w1 : 0.0f;
            cw1 += (o1 == 1) ? w1 : 0.0f;
            cw1 += (o2 == 1) ? w2 : 0.0f;
            cw2 += (o2 == 2) ? w2 : 0.0f;
        }
    }
    float rw0 = 0.f, rw1 = 0.f, rw2 = 0.f; int cnty = 0;
#pragma unroll
    for (int s = 0; s < SP; ++s) {
        float hh = hstart + ((float)s + 0.5f) * sub_h;
        if (hh > -1.0f && hh < (float)FH) {
            ++cnty;
            float y1f = floorf(hh);
            float dy  = hh - y1f;
            int   y1  = (int)y1f;
            int   y2  = (int)ceilf(hh);
            float w1  = (1.0f - dy) * ((y1 >= 0 && y1 < FH) ? 1.0f : 0.0f);
            float w2  = dy          * ((y2 >= 0 && y2 < FH) ? 1.0f : 0.0f);
            int o1 = y1 - Y0;
            int o2 = y2 - Y0;
            rw0 += (o1 == 0) ? w1 : 0.0f;
            rw1 += (o1 == 1) ? w1 : 0.0f;
            rw1 += (o2 == 1) ? w2 : 0.0f;
            rw2 += (o2 == 2) ? w2 : 0.0f;
        }
    }

    // ---- 3x3 window accumulate: 9 LDS pixel reads x 10 channels
    float4 a0 = make_float4(0.f,0.f,0.f,0.f);
    float4 a1 = make_float4(0.f,0.f,0.f,0.f);
    float  a8 = 0.f, a9 = 0.f;
    float rw[3] = {rw0, rw1, rw2};
    float cw[3] = {cw0, cw1, cw2};
#pragma unroll
    for (int j = 0; j < 3; ++j) {
        int y = min(max(Y0 + j, 0), FH - 1);
        float wy = rw[j];
#pragma unroll
        for (int i = 0; i < 3; ++i) {
            int x = min(max(X0 + i, 0), FW - 1);
            float w = wy * cw[i];
            const float4* lp = (const float4*)(lds + (y * FW + x) * CP);
            float4 f0 = lp[0];
            float4 f1 = lp[1];
            float4 f2 = lp[2];
            a0.x += w * f0.x; a0.y += w * f0.y; a0.z += w * f0.z; a0.w += w * f0.w;
            a1.x += w * f1.x; a1.y += w * f1.y; a1.z += w * f1.z; a1.w += w * f1.w;
            a8   += w * f2.x; a9   += w * f2.y;
        }
    }

    int cnt = cntx * cnty;
    float inv = (cnt > 0) ? 1.0f / (float)cnt : 0.0f;
    float res[C] = { a0.x*inv, a0.y*inv, a0.z*inv, a0.w*inv,
                     a1.x*inv, a1.y*inv, a1.z*inv, a1.w*inv,
                     a8*inv,   a9*inv };

    if (transposed) {
        // ws[(bin*C + c) * N + n] : lane-stride 4B, fully coalesced
        float* o = dst + (size_t)(bin * C) * N + n;
#pragma unroll
        for (int c = 0; c < C; ++c) o[(size_t)c * N] = res[c];
    } else {
        float* o = dst + (size_t)n * NOUTC + bin;
#pragma unroll
        for (int c = 0; c < C; ++c) o[c * NBIN] = res[c];
    }
}

// ---- ws (490 x N, row r = bin*10+c) -> out (N x 490, col = c*49+bin) ----
#define TJ 16
__global__ __launch_bounds__(256) void transpose_out(const float* __restrict__ ws,
                                                     float* __restrict__ out, int N) {
    __shared__ float t[NOUTC * (TJ + 1)];
    int n0  = blockIdx.x * TJ;
    int tid = threadIdx.x;
    const int total = NOUTC * TJ;
    for (int idx = tid; idx < total; idx += 256) {
        int r = idx / TJ;
        int j = idx - r * TJ;
        int n = n0 + j;
        t[r * (TJ + 1) + j] = (n < N) ? ws[(size_t)r * N + n] : 0.0f;
    }
    __syncthreads();
    for (int idx = tid; idx < total; idx += 256) {
        int j   = idx / NOUTC;
        int col = idx - j * NOUTC;
        int bin = col % NBIN;
        int c   = col / NBIN;
        int r   = bin * C + c;
        int n   = n0 + j;
        if (n < N) out[(size_t)n * NOUTC + col] = t[r * (TJ + 1) + j];
    }
}

extern "C" void kernel_launch(void* const* d_in, const int* in_sizes, int n_in,
                              void* d_out, int out_size, void* d_ws, size_t ws_size,
                              hipStream_t stream) {
    const float* ft   = (const float*)d_in[0];
    const float* rois = (const float*)d_in[1];
    float* out = (float*)d_out;
    int N = in_sizes[1] / 5;

    int blocksPerBin = (N + RPB - 1) / RPB;
    int nblocks = NBIN * blocksPerBin;
    size_t wsNeed = (size_t)NOUTC * N * sizeof(float);

    if (ws_size >= wsNeed) {
        float* ws = (float*)d_ws;
        roi_kernel<<<nblocks, RPB, 0, stream>>>(ft, rois, ws, N, blocksPerBin, 1);
        int tblocks = (N + TJ - 1) / TJ;
        transpose_out<<<tblocks, 256, 0, stream>>>(ws, out, N);
    } else {
        roi_kernel<<<nblocks, RPB, 0, stream>>>(ft, rois, out, N, blocksPerBin, 0);
    }
}

// Round 4
// 91.340 us; speedup vs baseline: 3.1418x; 1.2746x over previous
//
#include <hip/hip_runtime.h>

#define PH 7
#define PW 7
#define SP 4
#define C 10
#define CP 12              // channel pad -> 48B/pixel = 3 float4 quads
#define FH 34
#define FW 34
#define NBIN (PH*PW)       // 49
#define PLANE (FH*FW)      // 1156
#define NP (NBIN*PLANE)    // 56644 floats per channel
#define RPB 512            // rois per block
#define NOUTC (C*NBIN)     // 490
#define TJ 16              // rois per transpose tile

// ---- per-(roi, p) separable axis weights -------------------------------
// tabH[p*N+n] = {rw0, rw1, rw2, float(Y0*8+cnty)}  (h axis, p as ph)
// tabW[p*N+n] = {cw0, cw1, cw2, float(X0*8+cntx)}  (w axis, p as pw)
__global__ __launch_bounds__(256) void precompute(const float* __restrict__ rois,
                                                  float4* __restrict__ tabH,
                                                  float4* __restrict__ tabW, int N) {
#pragma clang fp contract(off)
    int t = blockIdx.x * 256 + threadIdx.x;
    if (t >= 7 * N) return;
    int n = t / 7;
    int p = t - n * 7;
    const float* r = rois + n * 5;
    float rsw = r[1] * 0.125f;
    float rsh = r[2] * 0.125f;
    float rew = r[3] * 0.125f;
    float reh = r[4] * 0.125f;
    float dh = reh - rsh; float roi_h = (dh > 0.1f) ? dh : 0.1f;
    float dw = rew - rsw; float roi_w = (dw > 0.1f) ? dw : 0.1f;
    float bin_h = roi_h / 7.0f;
    float bin_w = roi_w / 7.0f;
    float sub_h = bin_h / 4.0f;
    float sub_w = bin_w / 4.0f;
    float hstart = floorf(rsh + (float)p * bin_h);
    float wstart = floorf(rsw + (float)p * bin_w);
    int Y0 = (int)hstart;
    int X0 = (int)wstart;

    float rw0 = 0.f, rw1 = 0.f, rw2 = 0.f; int cnty = 0;
#pragma unroll
    for (int s = 0; s < SP; ++s) {
        float hh = hstart + ((float)s + 0.5f) * sub_h;
        if (hh > -1.0f && hh < (float)FH) {
            ++cnty;
            float y1f = floorf(hh);
            float dy  = hh - y1f;
            int   y1  = (int)y1f;
            int   y2  = (int)ceilf(hh);
            float w1  = (1.0f - dy) * ((y1 >= 0 && y1 < FH) ? 1.0f : 0.0f);
            float w2  = dy          * ((y2 >= 0 && y2 < FH) ? 1.0f : 0.0f);
            int o1 = y1 - Y0;
            int o2 = y2 - Y0;
            rw0 += (o1 == 0) ? w1 : 0.0f;
            rw1 += (o1 == 1) ? w1 : 0.0f;
            rw1 += (o2 == 1) ? w2 : 0.0f;
            rw2 += (o2 == 2) ? w2 : 0.0f;
        }
    }
    float cw0 = 0.f, cw1 = 0.f, cw2 = 0.f; int cntx = 0;
#pragma unroll
    for (int s = 0; s < SP; ++s) {
        float ww = wstart + ((float)s + 0.5f) * sub_w;
        if (ww > -1.0f && ww < (float)FW) {
            ++cntx;
            float x1f = floorf(ww);
            float dx  = ww - x1f;
            int   x1  = (int)x1f;
            int   x2  = (int)ceilf(ww);
            float w1  = (1.0f - dx) * ((x1 >= 0 && x1 < FW) ? 1.0f : 0.0f);
            float w2  = dx          * ((x2 >= 0 && x2 < FW) ? 1.0f : 0.0f);
            int o1 = x1 - X0;
            int o2 = x2 - X0;
            cw0 += (o1 == 0) ? w1 : 0.0f;
            cw1 += (o1 == 1) ? w1 : 0.0f;
            cw1 += (o2 == 1) ? w2 : 0.0f;
            cw2 += (o2 == 2) ? w2 : 0.0f;
        }
    }
    tabH[p * N + n] = make_float4(rw0, rw1, rw2, (float)(Y0 * 8 + cnty));
    tabW[p * N + n] = make_float4(cw0, cw1, cw2, (float)(X0 * 8 + cntx));
}

// ---- main: block = (bin, 512-roi chunk); slab in LDS; 3x3 window -------
__global__ __launch_bounds__(RPB, 4) void roi_kernel(const float* __restrict__ ft,
                                                     const float4* __restrict__ tabH,
                                                     const float4* __restrict__ tabW,
                                                     float* __restrict__ ws2,
                                                     int N, int blocksPerBin) {
#pragma clang fp contract(off)
    __shared__ float lds[PLANE * CP];          // 55808 B

    const int bin   = blockIdx.x / blocksPerBin;
    const int chunk = blockIdx.x % blocksPerBin;
    const int tid   = threadIdx.x;
    const int ph    = bin / PW;
    const int pw    = bin % PW;

    // stage slab, q-major: lanes read consecutive yx of one channel plane
    {
        float4* lds4 = (float4*)lds;
        for (int idx = tid; idx < 3 * PLANE; idx += RPB) {
            int q  = idx / PLANE;              // 0..2 -> channels 4q..4q+3
            int yx = idx - q * PLANE;
            const float* b0 = ft + ((size_t)(q * 4) * NBIN + bin) * PLANE + yx;
            float4 v;
            v.x = b0[0];
            v.y = b0[NP];
            v.z = (q < 2) ? b0[2 * NP] : 0.0f;
            v.w = (q < 2) ? b0[3 * NP] : 0.0f;
            lds4[yx * 3 + q] = v;
        }
    }
    __syncthreads();

    const int n = chunk * RPB + tid;
    if (n >= N) return;

    float4 th = tabH[ph * N + n];              // coalesced: lane stride 16B
    float4 tw = tabW[pw * N + n];
    int hp = (int)th.w; int Y0 = hp >> 3; int cnty = hp & 7;
    int wp = (int)tw.w; int X0 = wp >> 3; int cntx = wp & 7;
    float rw[3] = {th.x, th.y, th.z};
    float cw[3] = {tw.x, tw.y, tw.z};

    float4 a0 = make_float4(0.f,0.f,0.f,0.f);
    float4 a1 = make_float4(0.f,0.f,0.f,0.f);
    float  a8 = 0.f, a9 = 0.f;
#pragma unroll
    for (int j = 0; j < 3; ++j) {
        int y = min(max(Y0 + j, 0), FH - 1);
        float wy = rw[j];
#pragma unroll
        for (int i = 0; i < 3; ++i) {
            int x = min(max(X0 + i, 0), FW - 1);
            float w = wy * cw[i];
            const float4* lp = (const float4*)(lds + (y * FW + x) * CP);
            float4 f0 = lp[0];
            float4 f1 = lp[1];
            float4 f2 = lp[2];
            a0.x += w * f0.x; a0.y += w * f0.y; a0.z += w * f0.z; a0.w += w * f0.w;
            a1.x += w * f1.x; a1.y += w * f1.y; a1.z += w * f1.z; a1.w += w * f1.w;
            a8   += w * f2.x; a9   += w * f2.y;
        }
    }

    int cnt = cntx * cnty;
    float inv = (cnt > 0) ? 1.0f / (float)cnt : 0.0f;
    float res[C] = { a0.x*inv, a0.y*inv, a0.z*inv, a0.w*inv,
                     a1.x*inv, a1.y*inv, a1.z*inv, a1.w*inv,
                     a8*inv,   a9*inv };

    // ws2[(bin*C + c) * N + n] : lane-stride 4B, fully coalesced
    float* o = ws2 + (size_t)(bin * C) * N + n;
#pragma unroll
    for (int c = 0; c < C; ++c) o[(size_t)c * N] = res[c];
}

// ---- ws2 (490 x N, row r = bin*10+c) -> out (N x 490, col = c*49+bin) --
__global__ __launch_bounds__(256) void transpose_out(const float* __restrict__ ws2,
                                                     float* __restrict__ out, int N) {
    __shared__ float t[NOUTC * (TJ + 1)];      // 33320 B
    int n0  = blockIdx.x * TJ;
    int tid = threadIdx.x;
    bool fast = (n0 + TJ <= N) && ((n0 & 3) == 0) && ((N & 3) == 0);

    if (fast) {
        const float4* ws4 = (const float4*)ws2;
        int N4  = N >> 2;
        int n04 = n0 >> 2;
        for (int idx = tid; idx < NOUTC * 4; idx += 256) {
            int r = idx >> 2;
            int k = idx & 3;
            float4 v = ws4[(size_t)r * N4 + n04 + k];
            float* dst = &t[r * (TJ + 1) + 4 * k];
            dst[0] = v.x; dst[1] = v.y; dst[2] = v.z; dst[3] = v.w;
        }
    } else {
        for (int idx = tid; idx < NOUTC * TJ; idx += 256) {
            int r = idx / TJ;
            int j = idx - r * TJ;
            int n = n0 + j;
            t[r * (TJ + 1) + j] = (n < N) ? ws2[(size_t)r * N + n] : 0.0f;
        }
    }
    __syncthreads();

    if (fast) {
        float2* out2 = (float2*)out;
        for (int idx = tid; idx < TJ * (NOUTC / 2); idx += 256) {
            int j  = idx / (NOUTC / 2);
            int t2 = idx - j * (NOUTC / 2);
            int col0 = 2 * t2, col1 = col0 + 1;
            int c0 = col0 / NBIN, b0 = col0 - c0 * NBIN;
            int c1 = col1 / NBIN, b1 = col1 - c1 * NBIN;
            float2 v;
            v.x = t[(b0 * C + c0) * (TJ + 1) + j];
            v.y = t[(b1 * C + c1) * (TJ + 1) + j];
            out2[(size_t)(n0 + j) * (NOUTC / 2) + t2] = v;
        }
    } else {
        for (int idx = tid; idx < TJ * NOUTC; idx += 256) {
            int j   = idx / NOUTC;
            int col = idx - j * NOUTC;
            int c   = col / NBIN;
            int b   = col - c * NBIN;
            int n   = n0 + j;
            if (n < N) out[(size_t)n * NOUTC + col] = t[(b * C + c) * (TJ + 1) + j];
        }
    }
}

// ---- fallback (ws too small): inline math, direct strided store --------
__global__ __launch_bounds__(256) void roi_direct(const float* __restrict__ ft,
                                                  const float* __restrict__ rois,
                                                  float* __restrict__ out, int N) {
#pragma clang fp contract(off)
    int tid = blockIdx.x * blockDim.x + threadIdx.x;
    if (tid >= N * NBIN) return;
    int bin = tid % NBIN;
    int n   = tid / NBIN;
    int ph  = bin / PW;
    int pw  = bin % PW;
    const float* r = rois + n * 5;
    float rsw = r[1]*0.125f, rsh = r[2]*0.125f, rew = r[3]*0.125f, reh = r[4]*0.125f;
    float dh = reh - rsh; float roi_h = (dh > 0.1f) ? dh : 0.1f;
    float dw = rew - rsw; float roi_w = (dw > 0.1f) ? dw : 0.1f;
    float bin_h = roi_h / 7.0f, bin_w = roi_w / 7.0f;
    float sub_h = bin_h / 4.0f, sub_w = bin_w / 4.0f;
    float hstart = floorf(rsh + (float)ph * bin_h);
    float wstart = floorf(rsw + (float)pw * bin_w);
    int Y0 = (int)hstart, X0 = (int)wstart;
    float rw[3] = {0.f,0.f,0.f}, cw[3] = {0.f,0.f,0.f};
    int cnty = 0, cntx = 0;
    for (int s = 0; s < SP; ++s) {
        float hh = hstart + ((float)s + 0.5f) * sub_h;
        if (hh > -1.0f && hh < (float)FH) {
            ++cnty;
            float y1f = floorf(hh); float dy = hh - y1f;
            int y1 = (int)y1f, y2 = (int)ceilf(hh);
            float w1 = (1.0f-dy) * ((y1>=0&&y1<FH)?1.f:0.f);
            float w2 = dy        * ((y2>=0&&y2<FH)?1.f:0.f);
            if (y1-Y0>=0 && y1-Y0<3) rw[y1-Y0] += w1;
            if (y2-Y0>=0 && y2-Y0<3) rw[y2-Y0] += w2;
        }
        float ww = wstart + ((float)s + 0.5f) * sub_w;
        if (ww > -1.0f && ww < (float)FW) {
            ++cntx;
            float x1f = floorf(ww); float dx = ww - x1f;
            int x1 = (int)x1f, x2 = (int)ceilf(ww);
            float w1 = (1.0f-dx) * ((x1>=0&&x1<FW)?1.f:0.f);
            float w2 = dx        * ((x2>=0&&x2<FW)?1.f:0.f);
            if (x1-X0>=0 && x1-X0<3) cw[x1-X0] += w1;
            if (x2-X0>=0 && x2-X0<3) cw[x2-X0] += w2;
        }
    }
    float acc[C];
    for (int c = 0; c < C; ++c) acc[c] = 0.0f;
    const float* base = ft + (size_t)bin * PLANE;
    for (int j = 0; j < 3; ++j) {
        int y = min(max(Y0 + j, 0), FH - 1);
        for (int i = 0; i < 3; ++i) {
            int x = min(max(X0 + i, 0), FW - 1);
            float w = rw[j] * cw[i];
            int off = y * FW + x;
            for (int c = 0; c < C; ++c)
                acc[c] += w * base[(size_t)c * NP + off];
        }
    }
    int cnt = cntx * cnty;
    float inv = (cnt > 0) ? 1.0f / (float)cnt : 0.0f;
    float* o = out + (size_t)n * NOUTC + bin;
    for (int c = 0; c < C; ++c) o[c * NBIN] = acc[c] * inv;
}

extern "C" void kernel_launch(void* const* d_in, const int* in_sizes, int n_in,
                              void* d_out, int out_size, void* d_ws, size_t ws_size,
                              hipStream_t stream) {
    const float* ft   = (const float*)d_in[0];
    const float* rois = (const float*)d_in[1];
    float* out = (float*)d_out;
    int N = in_sizes[1] / 5;

    size_t ws2Bytes  = ((size_t)NOUTC * N * sizeof(float) + 255) & ~(size_t)255;
    size_t tabBytes  = (size_t)7 * N * sizeof(float4);
    size_t need      = ws2Bytes + 2 * tabBytes;

    if (ws_size >= need) {
        float*  ws2  = (float*)d_ws;
        float4* tabH = (float4*)((char*)d_ws + ws2Bytes);
        float4* tabW = tabH + (size_t)7 * N;

        int pblocks = (7 * N + 255) / 256;
        precompute<<<pblocks, 256, 0, stream>>>(rois, tabH, tabW, N);

        int blocksPerBin = (N + RPB - 1) / RPB;
        roi_kernel<<<NBIN * blocksPerBin, RPB, 0, stream>>>(ft, tabH, tabW, ws2,
                                                            N, blocksPerBin);

        int tblocks = (N + TJ - 1) / TJ;
        transpose_out<<<tblocks, 256, 0, stream>>>(ws2, out, N);
    } else {
        int total = N * NBIN;
        roi_direct<<<(total + 255) / 256, 256, 0, stream>>>(ft, rois, out, N);
    }
}